// Round 1
// baseline (906.850 us; speedup 1.0000x reference)
//
#include <hip/hip_runtime.h>
#include <hip/hip_bf16.h>

#define N_NODES 10000
#define IN_DIM 512
#define HID 128
#define MP 10112   // padded rows = 79*128 so MFMA tiles can read OOB rows safely

typedef __attribute__((ext_vector_type(8))) __bf16 bf16x8;
typedef __attribute__((ext_vector_type(4))) float f32x4;

// ---------- degree / normalization ----------
__global__ void k_init_deg(float* deg) {
    int i = blockIdx.x * 256 + threadIdx.x;
    if (i < N_NODES) deg[i] = 1.0f;  // self-loop
}

__global__ void k_count(const int* __restrict__ ei, float* deg, int E) {
    int e = blockIdx.x * 256 + threadIdx.x;
    if (e < E) atomicAdd(&deg[ei[E + e]], 1.0f);  // dst row = ei[1][e]
}

__global__ void k_dinv(const float* __restrict__ deg, float* __restrict__ dinv) {
    int i = blockIdx.x * 256 + threadIdx.x;
    if (i < N_NODES) dinv[i] = rsqrtf(deg[i]);  // deg >= 1 always
}

// ---------- casts ----------
__global__ void k_cast_x(const float* __restrict__ x, __hip_bfloat16* __restrict__ xb) {
    int idx = blockIdx.x * 256 + threadIdx.x;   // over MP*IN_DIM
    int i = idx >> 9;
    float v = (i < N_NODES) ? x[idx] : 0.0f;
    xb[idx] = __float2bfloat16(v);
}

__global__ void k_cast_wenc(const float* __restrict__ w, __hip_bfloat16* __restrict__ wT) {
    int idx = blockIdx.x * 256 + threadIdx.x;   // over HID*IN_DIM
    int n = idx & (HID - 1);
    int k = idx >> 7;
    wT[n * IN_DIM + k] = __float2bfloat16(w[k * HID + n]);
}

__global__ void k_cast_enc(const float* __restrict__ agg, const float* __restrict__ b_enc,
                           __hip_bfloat16* __restrict__ enc) {
    int idx = blockIdx.x * 256 + threadIdx.x;   // over MP*HID
    int i = idx >> 7, c = idx & (HID - 1);
    float v = (i < N_NODES) ? (agg[idx] + b_enc[c]) : 0.0f;
    enc[idx] = __float2bfloat16(v);
}

__global__ void k_cast_wdec(const float* __restrict__ wdec, __hip_bfloat16* __restrict__ wT) {
    int n = blockIdx.x * 256 + threadIdx.x;
    int k = blockIdx.y;
    if (n >= MP) return;
    float v = (n < N_NODES) ? wdec[(size_t)k * N_NODES + n] : 0.0f;
    wT[(size_t)n * HID + k] = __float2bfloat16(v);
}

// ---------- GCN aggregation ----------
__global__ void k_selfinit(const float* __restrict__ h, const float* __restrict__ dinv,
                           float* __restrict__ agg) {
    int idx = blockIdx.x * 256 + threadIdx.x;   // over N_NODES*HID
    int i = idx >> 7;
    float d = dinv[i];
    agg[idx] = h[idx] * d * d;
}

__global__ void k_scatter(const int* __restrict__ ei, const float* __restrict__ h,
                          const float* __restrict__ dinv, float* __restrict__ agg, int E) {
    int lane = threadIdx.x & 63;
    int eid = blockIdx.x * 4 + (threadIdx.x >> 6);
    if (eid >= E) return;
    int s = ei[eid];
    int d = ei[E + eid];
    float w = dinv[s] * dinv[d];
    float2 hv = ((const float2*)h)[(size_t)s * 64 + lane];
    float* base = agg + (size_t)d * HID + lane * 2;
    atomicAdd(base, hv.x * w);
    atomicAdd(base + 1, hv.y * w);
}

// ---------- bf16 MFMA GEMM: C[M,N] = op(A[M,K] @ BT[N,K]^T + bias) ----------
// A, BT row-major bf16 with K-contiguous rows; rows padded so OOB tile rows are readable.
// No LDS: each lane loads its 16B fragment directly (operands are L2-resident).
template<bool SIG>
__global__ __launch_bounds__(256) void gemm_bf16(
    const __hip_bfloat16* __restrict__ A, const __hip_bfloat16* __restrict__ BT,
    const float* __restrict__ bias, float* __restrict__ C,
    int M, int N, int K)
{
    int tid = threadIdx.x;
    int wv = tid >> 6, lane = tid & 63;
    int l16 = lane & 15, quad = lane >> 4;
    int m_w = blockIdx.y * 128 + (wv >> 1) * 64;
    int n_w = blockIdx.x * 128 + (wv & 1) * 64;
    f32x4 acc[4][4] = {};
    for (int kk = 0; kk < K; kk += 32) {
        int k0 = kk + quad * 8;
        bf16x8 a[4], b[4];
#pragma unroll
        for (int mi = 0; mi < 4; ++mi)
            a[mi] = *(const bf16x8*)(const void*)(A + (size_t)(m_w + mi * 16 + l16) * K + k0);
#pragma unroll
        for (int ni = 0; ni < 4; ++ni)
            b[ni] = *(const bf16x8*)(const void*)(BT + (size_t)(n_w + ni * 16 + l16) * K + k0);
#pragma unroll
        for (int mi = 0; mi < 4; ++mi)
#pragma unroll
            for (int ni = 0; ni < 4; ++ni)
                acc[mi][ni] = __builtin_amdgcn_mfma_f32_16x16x32_bf16(a[mi], b[ni], acc[mi][ni], 0, 0, 0);
    }
    // C/D layout: col = lane&15, row = quad*4 + reg  (verified mapping)
#pragma unroll
    for (int ni = 0; ni < 4; ++ni) {
        int n = n_w + ni * 16 + l16;
        if (n >= N) continue;
        float bv = SIG ? bias[n] : 0.0f;
#pragma unroll
        for (int mi = 0; mi < 4; ++mi) {
#pragma unroll
            for (int r = 0; r < 4; ++r) {
                int m = m_w + mi * 16 + quad * 4 + r;
                if (m < M) {
                    float z = acc[mi][ni][r];
                    if (SIG) z = 1.0f / (1.0f + __expf(-(z + bv)));
                    C[(size_t)m * N + n] = z;
                }
            }
        }
    }
}

extern "C" void kernel_launch(void* const* d_in, const int* in_sizes, int n_in,
                              void* d_out, int out_size, void* d_ws, size_t ws_size,
                              hipStream_t stream) {
    const float* x     = (const float*)d_in[0];
    const int*   ei    = (const int*)d_in[1];
    const float* W_enc = (const float*)d_in[2];
    const float* b_enc = (const float*)d_in[3];
    const float* W_dec = (const float*)d_in[4];
    const float* b_dec = (const float*)d_in[5];
    float* out = (float*)d_out;
    const int E = in_sizes[1] / 2;

    // carve workspace (~26 MB)
    char* p = (char*)d_ws;
    auto carve = [&](size_t bytes) -> char* {
        char* r = p;
        p += (bytes + 255) & ~(size_t)255;
        return r;
    };
    float* deg  = (float*)carve((size_t)N_NODES * 4);
    float* dinv = (float*)carve((size_t)N_NODES * 4);
    float* h    = (float*)carve((size_t)N_NODES * HID * 4);
    float* agg  = (float*)carve((size_t)N_NODES * HID * 4);
    __hip_bfloat16* xb    = (__hip_bfloat16*)carve((size_t)MP * IN_DIM * 2);
    __hip_bfloat16* wencT = (__hip_bfloat16*)carve((size_t)HID * IN_DIM * 2);
    __hip_bfloat16* encb  = (__hip_bfloat16*)carve((size_t)MP * HID * 2);
    __hip_bfloat16* wdecT = (__hip_bfloat16*)carve((size_t)MP * HID * 2);

    // degree + dinv
    k_init_deg<<<dim3(40), dim3(256), 0, stream>>>(deg);
    k_count<<<dim3((E + 255) / 256), dim3(256), 0, stream>>>(ei, deg, E);
    k_dinv<<<dim3(40), dim3(256), 0, stream>>>(deg, dinv);

    // encoder GEMM in bf16
    k_cast_x<<<dim3(MP * IN_DIM / 256), dim3(256), 0, stream>>>(x, xb);
    k_cast_wenc<<<dim3(HID * IN_DIM / 256), dim3(256), 0, stream>>>(W_enc, wencT);
    gemm_bf16<false><<<dim3(1, 79), dim3(256), 0, stream>>>(
        xb, wencT, (const float*)nullptr, h, N_NODES, HID, IN_DIM);

    // aggregation: self-loop init + edge scatter (fp32 atomics)
    k_selfinit<<<dim3(N_NODES * HID / 256), dim3(256), 0, stream>>>(h, dinv, agg);
    k_scatter<<<dim3((E + 3) / 4), dim3(256), 0, stream>>>(ei, h, dinv, agg, E);

    // decoder GEMM + bias + sigmoid in bf16
    k_cast_enc<<<dim3(MP * HID / 256), dim3(256), 0, stream>>>(agg, b_enc, encb);
    k_cast_wdec<<<dim3(40, HID), dim3(256), 0, stream>>>(W_dec, wdecT);
    gemm_bf16<true><<<dim3(79, 79), dim3(256), 0, stream>>>(
        encb, wdecT, b_dec, out, N_NODES, N_NODES, HID);
}

// Round 2
// 697.787 us; speedup vs baseline: 1.2996x; 1.2996x over previous
//
#include <hip/hip_runtime.h>
#include <hip/hip_bf16.h>

#define N_NODES 10000
#define IN_DIM 512
#define HID 128
#define MP 10112     // padded rows = 79*128 so MFMA tiles can read OOB rows safely
#define NPAD 10240   // 256*40, scan coverage

typedef __attribute__((ext_vector_type(8))) __bf16 bf16x8;
typedef __attribute__((ext_vector_type(4))) float f32x4;

// ---------- CSR build ----------
__global__ void k_zero_cnt(int* cnt) {
    int i = blockIdx.x * 256 + threadIdx.x;
    if (i < NPAD) cnt[i] = 0;
}

__global__ void k_hist(const int* __restrict__ ei, int* cnt, int E) {
    int e = blockIdx.x * 256 + threadIdx.x;
    if (e < E) atomicAdd(&cnt[ei[E + e]], 1);
}

// single block, 256 threads: exclusive scan of cnt[0..NPAD) -> base & cursor,
// plus dinv[i] = rsqrt(in_deg + 1) for the symmetric GCN norm.
__global__ void k_scan(const int* __restrict__ cnt, int* __restrict__ base,
                       int* __restrict__ cursor, float* __restrict__ dinv) {
    __shared__ int lds[256];
    int t = threadIdx.x;
    int loc[40];
    int sum = 0;
#pragma unroll
    for (int j = 0; j < 40; ++j) {
        int idx = t * 40 + j;
        int c = cnt[idx];
        loc[j] = sum;       // exclusive local prefix
        sum += c;
    }
    lds[t] = sum;
    __syncthreads();
    for (int off = 1; off < 256; off <<= 1) {
        int v = (t >= off) ? lds[t - off] : 0;
        __syncthreads();
        lds[t] += v;
        __syncthreads();
    }
    int ex = lds[t] - sum;  // exclusive block prefix for this thread
#pragma unroll
    for (int j = 0; j < 40; ++j) {
        int idx = t * 40 + j;
        int b = ex + loc[j];
        base[idx] = b;
        cursor[idx] = b;
        dinv[idx] = rsqrtf((float)cnt[idx] + 1.0f);
    }
}

__global__ void k_fill(const int* __restrict__ ei, const float* __restrict__ dinv,
                       int* cursor, int2* __restrict__ csr, int E) {
    int e = blockIdx.x * 256 + threadIdx.x;
    if (e >= E) return;
    int s = ei[e];
    int d = ei[E + e];
    int pos = atomicAdd(&cursor[d], 1);
    float w = dinv[s] * dinv[d];
    csr[pos] = make_int2(s, __float_as_int(w));
}

// one block (128 threads) per output row; thread t owns channel t.
// Fuses: self-loop term, CSR gather-accumulate, + b_enc, bf16 cast, zero-pad.
__global__ __launch_bounds__(128) void k_agg_enc(
    const float* __restrict__ h, const int2* __restrict__ csr,
    const int* __restrict__ base, const int* __restrict__ cnt,
    const float* __restrict__ dinv, const float* __restrict__ b_enc,
    __hip_bfloat16* __restrict__ enc)
{
    int i = blockIdx.x;
    int t = threadIdx.x;
    if (i >= N_NODES) {                      // pad rows for the MFMA decoder
        enc[(size_t)i * HID + t] = __float2bfloat16(0.0f);
        return;
    }
    float di = dinv[i];
    float acc = di * di * h[(size_t)i * HID + t];
    int j = base[i], end = j + cnt[i];
    for (; j < end; ++j) {
        int2 pr = csr[j];
        acc += __int_as_float(pr.y) * h[(size_t)pr.x * HID + t];
    }
    enc[(size_t)i * HID + t] = __float2bfloat16(acc + b_enc[t]);
}

// ---------- casts ----------
__global__ void k_cast_x(const float* __restrict__ x, __hip_bfloat16* __restrict__ xb) {
    int idx = blockIdx.x * 256 + threadIdx.x;   // over MP*IN_DIM
    int i = idx >> 9;
    float v = (i < N_NODES) ? x[idx] : 0.0f;
    xb[idx] = __float2bfloat16(v);
}

__global__ void k_cast_wenc(const float* __restrict__ w, __hip_bfloat16* __restrict__ wT) {
    int idx = blockIdx.x * 256 + threadIdx.x;   // over HID*IN_DIM
    int n = idx & (HID - 1);
    int k = idx >> 7;
    wT[n * IN_DIM + k] = __float2bfloat16(w[k * HID + n]);
}

__global__ void k_cast_wdec(const float* __restrict__ wdec, __hip_bfloat16* __restrict__ wT) {
    int n = blockIdx.x * 256 + threadIdx.x;
    int k = blockIdx.y;
    if (n >= MP) return;
    float v = (n < N_NODES) ? wdec[(size_t)k * N_NODES + n] : 0.0f;
    wT[(size_t)n * HID + k] = __float2bfloat16(v);
}

// ---------- bf16 MFMA GEMM: C[M,N] = op(A[M,K] @ BT[N,K]^T + bias) ----------
template<bool SIG>
__global__ __launch_bounds__(256) void gemm_bf16(
    const __hip_bfloat16* __restrict__ A, const __hip_bfloat16* __restrict__ BT,
    const float* __restrict__ bias, float* __restrict__ C,
    int M, int N, int K)
{
    int tid = threadIdx.x;
    int wv = tid >> 6, lane = tid & 63;
    int l16 = lane & 15, quad = lane >> 4;
    int m_w = blockIdx.y * 128 + (wv >> 1) * 64;
    int n_w = blockIdx.x * 128 + (wv & 1) * 64;
    f32x4 acc[4][4] = {};
    for (int kk = 0; kk < K; kk += 32) {
        int k0 = kk + quad * 8;
        bf16x8 a[4], b[4];
#pragma unroll
        for (int mi = 0; mi < 4; ++mi)
            a[mi] = *(const bf16x8*)(const void*)(A + (size_t)(m_w + mi * 16 + l16) * K + k0);
#pragma unroll
        for (int ni = 0; ni < 4; ++ni)
            b[ni] = *(const bf16x8*)(const void*)(BT + (size_t)(n_w + ni * 16 + l16) * K + k0);
#pragma unroll
        for (int mi = 0; mi < 4; ++mi)
#pragma unroll
            for (int ni = 0; ni < 4; ++ni)
                acc[mi][ni] = __builtin_amdgcn_mfma_f32_16x16x32_bf16(a[mi], b[ni], acc[mi][ni], 0, 0, 0);
    }
    // C/D layout: col = lane&15, row = quad*4 + reg
#pragma unroll
    for (int ni = 0; ni < 4; ++ni) {
        int n = n_w + ni * 16 + l16;
        if (n >= N) continue;
        float bv = SIG ? bias[n] : 0.0f;
#pragma unroll
        for (int mi = 0; mi < 4; ++mi) {
#pragma unroll
            for (int r = 0; r < 4; ++r) {
                int m = m_w + mi * 16 + quad * 4 + r;
                if (m < M) {
                    float z = acc[mi][ni][r];
                    if (SIG) z = 1.0f / (1.0f + __expf(-(z + bv)));
                    C[(size_t)m * N + n] = z;
                }
            }
        }
    }
}

extern "C" void kernel_launch(void* const* d_in, const int* in_sizes, int n_in,
                              void* d_out, int out_size, void* d_ws, size_t ws_size,
                              hipStream_t stream) {
    const float* x     = (const float*)d_in[0];
    const int*   ei    = (const int*)d_in[1];
    const float* W_enc = (const float*)d_in[2];
    const float* b_enc = (const float*)d_in[3];
    const float* W_dec = (const float*)d_in[4];
    const float* b_dec = (const float*)d_in[5];
    float* out = (float*)d_out;
    const int E = in_sizes[1] / 2;

    // carve workspace (~22 MB)
    char* p = (char*)d_ws;
    auto carve = [&](size_t bytes) -> char* {
        char* r = p;
        p += (bytes + 255) & ~(size_t)255;
        return r;
    };
    int*   cnt    = (int*)carve((size_t)NPAD * 4);
    int*   base   = (int*)carve((size_t)NPAD * 4);
    int*   cursor = (int*)carve((size_t)NPAD * 4);
    float* dinv   = (float*)carve((size_t)NPAD * 4);
    int2*  csr    = (int2*)carve((size_t)E * 8);
    float* h      = (float*)carve((size_t)N_NODES * HID * 4);
    __hip_bfloat16* xb    = (__hip_bfloat16*)carve((size_t)MP * IN_DIM * 2);
    __hip_bfloat16* wencT = (__hip_bfloat16*)carve((size_t)HID * IN_DIM * 2);
    __hip_bfloat16* encb  = (__hip_bfloat16*)carve((size_t)MP * HID * 2);
    __hip_bfloat16* wdecT = (__hip_bfloat16*)carve((size_t)MP * HID * 2);

    // CSR build (counting sort by dst) + dinv
    k_zero_cnt<<<dim3(NPAD / 256), dim3(256), 0, stream>>>(cnt);
    k_hist<<<dim3((E + 255) / 256), dim3(256), 0, stream>>>(ei, cnt, E);
    k_scan<<<dim3(1), dim3(256), 0, stream>>>(cnt, base, cursor, dinv);
    k_fill<<<dim3((E + 255) / 256), dim3(256), 0, stream>>>(ei, dinv, cursor, csr, E);

    // encoder GEMM in bf16
    k_cast_x<<<dim3(MP * IN_DIM / 256), dim3(256), 0, stream>>>(x, xb);
    k_cast_wenc<<<dim3(HID * IN_DIM / 256), dim3(256), 0, stream>>>(W_enc, wencT);
    gemm_bf16<false><<<dim3(1, 79), dim3(256), 0, stream>>>(
        xb, wencT, (const float*)nullptr, h, N_NODES, HID, IN_DIM);

    // fused aggregate + bias + bf16 cast (gather over CSR, no atomics)
    k_agg_enc<<<dim3(MP), dim3(128), 0, stream>>>(h, csr, base, cnt, dinv, b_enc, encb);

    // decoder GEMM + bias + sigmoid in bf16
    k_cast_wdec<<<dim3(40, HID), dim3(256), 0, stream>>>(W_dec, wdecT);
    gemm_bf16<true><<<dim3(79, 79), dim3(256), 0, stream>>>(
        encb, wdecT, b_dec, out, N_NODES, N_NODES, HID);
}